// Round 4
// baseline (49.938 us; speedup 1.0000x reference)
//
#include <hip/hip_runtime.h>

// Bilateral-grid slicing, LDS-staged, v2b (fixed NT builtin types).
//   grid : (B=16, C=12, D=8, H=16, W=16) f32
//   guide: (B=16, 1, 512, 512) f32
//   out  : (B=16, C=12, 512, 512) f32
//
// Block = 256 threads = 4 rows of one batch. All 4 rows share iy0
// (32-row y-stripes, blocks never straddle), so only 2 y-slices staged:
//   S[c][y][x][z] : dword idx = c*288 + y*144 + x*9 + z   (13.5 KB)
// Clamp tricks make dx=9, dy=144 compile-time, so all 8 trilinear corners
// are immediate offsets {0,1,9,10,144,145,153,154} from one base VGPR
// -> 4 ds_read2_b32 per pixel-channel, z-lerp in registers.

typedef float vfloat4 __attribute__((ext_vector_type(4)));

constexpr int C = 12, D = 8, H = 16, W = 16, GH = 512, GW = 512;
constexpr int XST = 9;                // x stride in LDS dwords (8 z + 1 pad)
constexpr int YST = 16 * XST;         // 144
constexpr int CST = 2 * YST;          // 288
constexpr int LDS_FLOATS = C * CST;   // 3456 (13.5 KB)

__global__ __launch_bounds__(256, 6) void slice_kernel(
    const float* __restrict__ grid,
    const float* __restrict__ guide,
    float* __restrict__ out)
{
    __shared__ float S[LDS_FLOATS];
    const int t   = threadIdx.x;
    const int bid = blockIdx.x;
    const int b   = bid >> 7;            // 128 blocks per batch
    const int h0  = (bid & 127) << 2;    // 4 rows per block

    // block-uniform y cell (rows h0..h0+3 never straddle an iy0 boundary)
    float iy_f = fminf(fmaxf((float)h0 * 0.03125f - 0.5f, 0.0f), 15.0f);
    const int y0 = min((int)iy_f, H - 2);     // [0,14]

    // ---- stage grid (2 y-slices) -> LDS : 768 float4 chunks, 3 iters ----
    const float* gb = grid + (size_t)b * (C * D * H * W);
#pragma unroll
    for (int iter = 0; iter < 3; ++iter) {
        int i  = t + (iter << 8);        // 0..767
        int x4 = i & 3;                  // float4 chunk within row of 16 x
        int z  = (i >> 2) & 7;
        int y  = (i >> 5) & 1;
        int c  = i >> 6;
        const float4 v = *reinterpret_cast<const float4*>(
            gb + ((c * D + z) * H + (y0 + y)) * W + (x4 << 2));
        int x0 = x4 << 2;
        int dbase = c * CST + y * YST + z;
        S[dbase + (x0 + 0) * XST] = v.x;
        S[dbase + (x0 + 1) * XST] = v.y;
        S[dbase + (x0 + 2) * XST] = v.z;
        S[dbase + (x0 + 3) * XST] = v.w;
    }
    __syncthreads();

#pragma unroll
    for (int qq = 0; qq < 2; ++qq) {
        const int lpx = (t + (qq << 8)) << 2;   // local pixel 0..2047
        const int row = lpx >> 9;
        const int w0  = lpx & (GW - 1);
        const int h   = h0 + row;

        const vfloat4 g4 = __builtin_nontemporal_load(
            reinterpret_cast<const vfloat4*>(guide + (((b << 9) + h) << 9) + w0));
        const float gz[4] = {g4.x, g4.y, g4.z, g4.w};

        // y weight (uniform per row); fy in [0,1] after clamp trick
        float iyr = fminf(fmaxf((float)h * 0.03125f - 0.5f, 0.0f), 15.0f);
        const float fy = iyr - (float)y0;

        int   pb[4];
        float fz[4], w00[4], w01[4], w10[4], w11[4];
#pragma unroll
        for (int j = 0; j < 4; ++j) {
            float ix = fminf(fmaxf((float)(w0 + j) * 0.03125f - 0.5f, 0.0f), 15.0f);
            int   x0c = min((int)ix, W - 2);
            float fx  = ix - (float)x0c;

            float iz = fminf(fmaxf(gz[j] * 4.0f + 3.5f, 0.0f), 7.0f);
            int   z0c = min((int)iz, D - 2);
            fz[j] = iz - (float)z0c;

            pb[j] = x0c * XST + z0c;
            float fy0 = 1.0f - fy, fx0 = 1.0f - fx;
            w00[j] = fy0 * fx0;
            w01[j] = fy0 * fx;
            w10[j] = fy  * fx0;
            w11[j] = fy  * fx;
        }

        const size_t obase = (((size_t)b * C) * GH + h) * GW + w0;
#pragma unroll
        for (int c = 0; c < C; ++c) {
            float acc[4];
#pragma unroll
            for (int j = 0; j < 4; ++j) {
                const int base = c * CST + pb[j];
                float a0 = S[base],             a1 = S[base + 1];
                float b0 = S[base + XST],       b1 = S[base + XST + 1];
                float c0 = S[base + YST],       c1 = S[base + YST + 1];
                float d0 = S[base + YST + XST], d1 = S[base + YST + XST + 1];
                float f  = fz[j];
                float va = a0 + f * (a1 - a0);
                float vb = b0 + f * (b1 - b0);
                float vc = c0 + f * (c1 - c0);
                float vd = d0 + f * (d1 - d0);
                acc[j] = ((w00[j] * va + w01[j] * vb) + w10[j] * vc) + w11[j] * vd;
            }
            vfloat4 r;
            r.x = acc[0]; r.y = acc[1]; r.z = acc[2]; r.w = acc[3];
            __builtin_nontemporal_store(r,
                reinterpret_cast<vfloat4*>(out + obase + (size_t)c * (GH * GW)));
        }
    }
}

extern "C" void kernel_launch(void* const* d_in, const int* in_sizes, int n_in,
                              void* d_out, int out_size, void* d_ws, size_t ws_size,
                              hipStream_t stream) {
    const float* grid  = (const float*)d_in[0];
    const float* guide = (const float*)d_in[1];
    float* out = (float*)d_out;
    (void)in_sizes; (void)n_in; (void)out_size; (void)d_ws; (void)ws_size;

    dim3 block(256);
    dim3 gridDim(2048);   // 16 batches * 128 row-groups
    hipLaunchKernelGGL(slice_kernel, gridDim, block, 0, stream, grid, guide, out);
}

// Round 5
// 40.761 us; speedup vs baseline: 1.2251x; 1.2251x over previous
//
#include <hip/hip_runtime.h>

// Bilateral-grid slicing, v3: y-pre-lerped LDS staging.
//   grid : (B=16, C=12, D=8, H=16, W=16) f32
//   guide: (B=16, 1, 512, 512) f32
//   out  : (B=16, C=12, 512, 512) f32
//
// Block = 256 threads = 2 rows of one batch (1 quad of 4 px per thread).
// Rows 2k,2k+1 share y0 (transitions at h=32n+16, even), so staging
// pre-lerps y per row:  L[row][c][x][z] = G[y0]*(1-fy_row) + G[y0+1]*fy_row
// LDS layout dword idx = row*1728 + c*144 + x*9 + z  (13.5 KB).
// Per pixel-channel: bilinear (x,z) = 2 ds_read2_b32 + z/x lerps.
// (R3 post-mortem: NT stores + launch_bounds(256,6) regressed 43->50; reverted.)

typedef float vfloat4 __attribute__((ext_vector_type(4)));

constexpr int C = 12, D = 8, H = 16, W = 16, GH = 512, GW = 512;
constexpr int XST  = 9;            // x stride in LDS dwords (8 z + 1 pad)
constexpr int CSTR = 16 * XST;     // per-channel stride = 144
constexpr int RST  = C * CSTR;     // per-row stride = 1728
constexpr int LDS_FLOATS = 2 * RST;

__global__ void slice_kernel(const float* __restrict__ grid,
                             const float* __restrict__ guide,
                             float* __restrict__ out)
{
    __shared__ float S[LDS_FLOATS];
    const int t   = threadIdx.x;
    const int bid = blockIdx.x;
    const int b   = bid >> 8;            // 256 blocks per batch
    const int h0  = (bid & 255) << 1;    // 2 rows per block

    // rows h0, h0+1 share y0; per-row fractional weights
    float iyr0 = fminf(fmaxf((float)h0       * 0.03125f - 0.5f, 0.0f), 15.0f);
    float iyr1 = fminf(fmaxf((float)(h0 + 1) * 0.03125f - 0.5f, 0.0f), 15.0f);
    const int   y0  = min((int)iyr0, H - 2);   // [0,14]
    const float fy0 = iyr0 - (float)y0;        // [0,1]
    const float fy1 = iyr1 - (float)y0;        // [0,1]

    // this thread's quad (threads 0-127 -> row 0, 128-255 -> row 1)
    const int row = t >> 7;
    const int w0  = (t & 127) << 2;
    const int h   = h0 + row;

    // hoist guide load (independent of staging)
    const vfloat4 g4 = *reinterpret_cast<const vfloat4*>(
        guide + (((b << 9) + h) << 9) + w0);

    // ---- stage: 384 float4-chunks, y-lerped into both row slices ----
    const float* gb = grid + (size_t)b * (C * D * H * W);
#pragma unroll
    for (int iter = 0; iter < 2; ++iter) {
        int i = t + (iter << 8);
        if (i < 384) {
            int x4 = i & 3;              // float4 chunk within 16-x row
            int z  = (i >> 2) & 7;
            int c  = i >> 5;
            const float* p0 = gb + ((c * D + z) * H + y0) * W + (x4 << 2);
            const vfloat4 v0 = *reinterpret_cast<const vfloat4*>(p0);
            const vfloat4 v1 = *reinterpret_cast<const vfloat4*>(p0 + W);
            const vfloat4 dv = v1 - v0;
            const vfloat4 r0 = v0 + fy0 * dv;
            const vfloat4 r1 = v0 + fy1 * dv;
            int x0 = x4 << 2;
            int d0 = c * CSTR + z;
            S[d0 + (x0 + 0) * XST] = r0.x;
            S[d0 + (x0 + 1) * XST] = r0.y;
            S[d0 + (x0 + 2) * XST] = r0.z;
            S[d0 + (x0 + 3) * XST] = r0.w;
            int d1 = d0 + RST;
            S[d1 + (x0 + 0) * XST] = r1.x;
            S[d1 + (x0 + 1) * XST] = r1.y;
            S[d1 + (x0 + 2) * XST] = r1.z;
            S[d1 + (x0 + 3) * XST] = r1.w;
        }
    }
    __syncthreads();

    // ---- per-pixel x/z setup ----
    const float gz[4] = {g4.x, g4.y, g4.z, g4.w};
    int   pb[4];
    float fzv[4], wx0[4], wx1[4];
#pragma unroll
    for (int j = 0; j < 4; ++j) {
        float ix = fminf(fmaxf((float)(w0 + j) * 0.03125f - 0.5f, 0.0f), 15.0f);
        int   x0c = min((int)ix, W - 2);
        float fx  = ix - (float)x0c;

        float iz = fminf(fmaxf(gz[j] * 4.0f + 3.5f, 0.0f), 7.0f);
        int   z0c = min((int)iz, D - 2);
        fzv[j] = iz - (float)z0c;

        pb[j]  = row * RST + x0c * XST + z0c;
        wx1[j] = fx;
        wx0[j] = 1.0f - fx;
    }

    const size_t obase = (((size_t)b * C) * GH + h) * GW + w0;
#pragma unroll
    for (int c = 0; c < C; ++c) {
        float acc[4];
#pragma unroll
        for (int j = 0; j < 4; ++j) {
            const int base = c * CSTR + pb[j];
            float a0 = S[base],       a1 = S[base + 1];
            float b0 = S[base + XST], b1 = S[base + XST + 1];
            float f  = fzv[j];
            float va = a0 + f * (a1 - a0);
            float vb = b0 + f * (b1 - b0);
            acc[j] = wx0[j] * va + wx1[j] * vb;
        }
        vfloat4 r;
        r.x = acc[0]; r.y = acc[1]; r.z = acc[2]; r.w = acc[3];
        *reinterpret_cast<vfloat4*>(out + obase + (size_t)c * (GH * GW)) = r;
    }
}

extern "C" void kernel_launch(void* const* d_in, const int* in_sizes, int n_in,
                              void* d_out, int out_size, void* d_ws, size_t ws_size,
                              hipStream_t stream) {
    const float* grid  = (const float*)d_in[0];
    const float* guide = (const float*)d_in[1];
    float* out = (float*)d_out;
    (void)in_sizes; (void)n_in; (void)out_size; (void)d_ws; (void)ws_size;

    dim3 block(256);
    dim3 gridDim(4096);   // 16 batches * 256 two-row groups
    hipLaunchKernelGGL(slice_kernel, gridDim, block, 0, stream, grid, guide, out);
}